// Round 3
// baseline (314.205 us; speedup 1.0000x reference)
//
#include <hip/hip_runtime.h>
#include <hip/hip_bf16.h>
#include <hip/hip_fp8.h>
#include <stdint.h>

#define G_ 4
#define N_ 4096
#define D_ 1024            // K in elements = bytes (fp8)
#define BK_ 128            // K-bytes per LDS tile = one 16x16x128 MFMA K
#define KT_ (D_ / BK_)     // 8 K-iterations
#define MAX_LOGIT_SCALE_F 4.605170185988091f
#define ZSCALE 16.0f       // pre-quantization scale; logits /= ZSCALE^2

typedef float f32x4 __attribute__((ext_vector_type(4)));
typedef int i32x8 __attribute__((ext_vector_type(8)));
typedef __bf16 bf16;

#define AS1 __attribute__((address_space(1)))
#define AS3 __attribute__((address_space(3)))

// ---------------------------------------------------------------------------
// Mask dtype detection (reference dtype bool; harness may store bytes or i32).
// ---------------------------------------------------------------------------
__device__ inline bool mask_is_bytes(const void* masks) {
  const unsigned char* b = (const unsigned char*)masks;
  return (b[1] | b[2] | b[3]) != 0;
}
__device__ inline float mask_val(const void* masks, int idx, bool as_bytes) {
  if (as_bytes) return ((const unsigned char*)masks)[idx] ? 1.0f : 0.0f;
  return ((const int*)masks)[idx] ? 1.0f : 0.0f;
}

// ---------------------------------------------------------------------------
// fp8 e4m3 pack of 4 floats -> u32 (HW cvt if available).
// ---------------------------------------------------------------------------
__device__ inline unsigned int pack4_e4m3(float a, float b, float c, float d) {
#if defined(__has_builtin) && __has_builtin(__builtin_amdgcn_cvt_pk_fp8_f32)
  unsigned int pk = (unsigned int)__builtin_amdgcn_cvt_pk_fp8_f32(a, b, 0, false);
  pk = (unsigned int)__builtin_amdgcn_cvt_pk_fp8_f32(c, d, (int)pk, true);
  return pk;
#else
  __hip_fp8_e4m3 qa(a), qb(b), qc(c), qd(d);
  return (unsigned int)qa.__x | ((unsigned int)qb.__x << 8) |
         ((unsigned int)qc.__x << 16) | ((unsigned int)qd.__x << 24);
#endif
}

// ---------------------------------------------------------------------------
// Kernel 1: L2-normalize rows, scale by 16, quantize to fp8 e4m3, and store
// PRE-SWIZZLED: element e of a row goes to file byte (e ^ ((row&7)<<4))
// within its 128-B K-chunk (XOR touches bits 4-6 only). This makes the
// linear global_load_lds staging produce a bank-conflict-free LDS layout
// (T2 swizzle with both sides consistent — rule #21).
// ---------------------------------------------------------------------------
__global__ __launch_bounds__(256) void norm_kernel(
    const float* __restrict__ merged, const float* __restrict__ orig,
    unsigned char* __restrict__ zq) {
  const int row = blockIdx.x;                 // 0 .. 2*G*N-1
  const int GN = G_ * N_;
  const float* src = (row < GN) ? (merged + (size_t)row * D_)
                                : (orig + (size_t)(row - GN) * D_);
  const int tid = threadIdx.x;                // 256 threads, 4 elems each
  float4 v = reinterpret_cast<const float4*>(src)[tid];
  float ss = v.x * v.x + v.y * v.y + v.z * v.z + v.w * v.w;
#pragma unroll
  for (int off = 32; off; off >>= 1) ss += __shfl_down(ss, off, 64);
  __shared__ float wsum[4];
  if ((tid & 63) == 0) wsum[tid >> 6] = ss;
  __syncthreads();
  const float tot = wsum[0] + wsum[1] + wsum[2] + wsum[3];
  const float inv = ZSCALE / fmaxf(sqrtf(tot), 1e-12f);
  const unsigned int pk =
      pack4_e4m3(v.x * inv, v.y * inv, v.z * inv, v.w * inv);
  // 4 consecutive bytes at e0=tid*4 stay inside one 16-B granule, so one
  // u32 store at the XOR'd offset places all 4 correctly.
  const int e0 = tid * 4;
  const int off = e0 ^ ((row & 7) << 4);
  *reinterpret_cast<unsigned int*>(zq + (size_t)row * D_ + off) = pk;
}

// ---------------------------------------------------------------------------
// Kernel 2: 128x128-tile MX-fp8 GEMM (z1 . z2^T per group) + fused SigLIP
// loss. R1-proven m97 structure: 4 waves (2x2 of 64x64), single-buffered
// LDS, 2 barriers/K-iter, global_load_lds width 16. MFMA:
// mfma_scale_f32_16x16x128_f8f6f4, fp8/fp8, unit scales (E8M0 127).
// LDS reads XOR-deswizzle (data pre-swizzled by norm_kernel) -> 2-way banks.
// ---------------------------------------------------------------------------
__global__ __launch_bounds__(256) void gemm_loss_kernel(
    const unsigned char* __restrict__ z1q, const unsigned char* __restrict__ z2q,
    const void* __restrict__ masks,
    const float* __restrict__ p_ls, const float* __restrict__ p_lb,
    float* __restrict__ partial) {
  const int g  = blockIdx.z;
  const int tm = blockIdx.y * 128;
  const int tn = blockIdx.x * 128;
  const unsigned char* A = z1q + ((size_t)g * N_ + tm) * D_;
  const unsigned char* B = z2q + ((size_t)g * N_ + tn) * D_;

  __shared__ __align__(16) unsigned char As[128 * BK_];  // 16 KiB
  __shared__ __align__(16) unsigned char Bs[128 * BK_];  // 16 KiB

  const int tid  = threadIdx.x;
  const int wave = tid >> 6;
  const int lane = tid & 63;
  const int wr = (wave >> 1) * 64;
  const int wc = (wave & 1) * 64;

  f32x4 acc[4][4] = {};

  const int rlo = lane & 15;          // fragment row within 16
  const int kb0 = (lane >> 4) * 32;   // this lane's 32-byte K-chunk base

  for (int kt = 0; kt < KT_; ++kt) {
    const int k0 = kt * BK_;
    // stage A,B tiles: 1024 granules of 16 B each, 4 rounds x 256 threads.
    // dest base is wave-uniform (HW adds lane*16); source is per-lane and
    // already swizzle-permuted in the z file, so linear copy == swizzled LDS.
#pragma unroll
    for (int r = 0; r < 4; ++r) {
      const int gr = r * 256 + tid;   // granule index; row = gr/8
      const unsigned char* sa = A + (size_t)(gr >> 3) * D_ + k0 + (gr & 7) * 16;
      __builtin_amdgcn_global_load_lds(
          (const AS1 void*)sa, (AS3 void*)(As + r * 4096 + wave * 1024), 16, 0, 0);
      const unsigned char* sb = B + (size_t)(gr >> 3) * D_ + k0 + (gr & 7) * 16;
      __builtin_amdgcn_global_load_lds(
          (const AS1 void*)sb, (AS3 void*)(Bs + r * 4096 + wave * 1024), 16, 0, 0);
    }
    __syncthreads();  // compiler drains vmcnt before s_barrier

    i32x8 af[4], bf[4];
#pragma unroll
    for (int i = 0; i < 4; ++i) {
      const int row = wr + i * 16 + rlo;
      const int sw = (row & 7) << 4;
      const int4 lo = *reinterpret_cast<const int4*>(As + row * BK_ + (kb0 ^ sw));
      const int4 hi = *reinterpret_cast<const int4*>(As + row * BK_ + ((kb0 + 16) ^ sw));
      af[i][0] = lo.x; af[i][1] = lo.y; af[i][2] = lo.z; af[i][3] = lo.w;
      af[i][4] = hi.x; af[i][5] = hi.y; af[i][6] = hi.z; af[i][7] = hi.w;
    }
#pragma unroll
    for (int j = 0; j < 4; ++j) {
      const int row = wc + j * 16 + rlo;
      const int sw = (row & 7) << 4;
      const int4 lo = *reinterpret_cast<const int4*>(Bs + row * BK_ + (kb0 ^ sw));
      const int4 hi = *reinterpret_cast<const int4*>(Bs + row * BK_ + ((kb0 + 16) ^ sw));
      bf[j][0] = lo.x; bf[j][1] = lo.y; bf[j][2] = lo.z; bf[j][3] = lo.w;
      bf[j][4] = hi.x; bf[j][5] = hi.y; bf[j][6] = hi.z; bf[j][7] = hi.w;
    }

#pragma unroll
    for (int i = 0; i < 4; ++i)
#pragma unroll
      for (int j = 0; j < 4; ++j)
        acc[i][j] = __builtin_amdgcn_mfma_scale_f32_16x16x128_f8f6f4(
            af[i], bf[j], acc[i][j],
            0, 0,        // cbsz = fp8(e4m3) A, blgp = fp8(e4m3) B
            0, 127,      // opsel_a, scale_a = E8M0 1.0
            0, 127);     // opsel_b, scale_b = E8M0 1.0
    __syncthreads();
  }

  // ---- fused loss epilogue (C/D layout shape-determined: m89/m127) ----
  const float scale = expf(fminf(p_ls[0], MAX_LOGIT_SCALE_F));
  const float s256  = scale * (1.0f / (ZSCALE * ZSCALE));
  const float lbias = p_lb[0];
  const bool as_bytes = mask_is_bytes(masks);
  const int mbase = g * N_;

  const int row0 = tm + wr + ((lane >> 4) << 2);  // + i*16 + j
  const int col0 = tn + wc + (lane & 15);         // + fc*16

  float mR[4][4], mC[4];
#pragma unroll
  for (int i = 0; i < 4; ++i)
#pragma unroll
    for (int j = 0; j < 4; ++j)
      mR[i][j] = mask_val(masks, mbase + row0 + i * 16 + j, as_bytes);
#pragma unroll
  for (int fc = 0; fc < 4; ++fc)
    mC[fc] = mask_val(masks, mbase + col0 + fc * 16, as_bytes);

  float lsum = 0.0f;
#pragma unroll
  for (int i = 0; i < 4; ++i) {
#pragma unroll
    for (int fc = 0; fc < 4; ++fc) {
#pragma unroll
      for (int j = 0; j < 4; ++j) {
        const float v = acc[i][fc][j] * s256 + lbias;   // logit
        const int r = row0 + i * 16 + j;
        const int c = col0 + fc * 16;
        const float u = (r == c) ? -v : v;              // -label*logit
        const float loss = fmaxf(u, 0.0f) + __logf(1.0f + __expf(-fabsf(u)));
        lsum += mR[i][j] * mC[fc] * loss;
      }
    }
  }

#pragma unroll
  for (int off = 32; off; off >>= 1) lsum += __shfl_down(lsum, off, 64);
  __shared__ float red[4];
  if (lane == 0) red[wave] = lsum;
  __syncthreads();
  if (tid == 0)
    partial[(size_t)g * 1024 + blockIdx.y * 32 + blockIdx.x] =
        red[0] + red[1] + red[2] + red[3];
}

// ---------------------------------------------------------------------------
// Kernel 3: n_sel per group + masked mean over valid groups -> scalar.
// ---------------------------------------------------------------------------
__global__ __launch_bounds__(256) void finalize_kernel(
    const void* __restrict__ masks, const float* __restrict__ partial,
    float* __restrict__ out) {
  const int tid = threadIdx.x;
  const bool as_bytes = mask_is_bytes(masks);
  __shared__ float redc[G_][4];
  __shared__ float redp[G_][4];
  for (int g = 0; g < G_; ++g) {
    float cnt = 0.0f, ps = 0.0f;
    for (int i = tid; i < N_; i += 256) cnt += mask_val(masks, g * N_ + i, as_bytes);
    for (int i = tid; i < 1024; i += 256) ps += partial[g * 1024 + i];
#pragma unroll
    for (int off = 32; off; off >>= 1) {
      cnt += __shfl_down(cnt, off, 64);
      ps  += __shfl_down(ps,  off, 64);
    }
    if ((tid & 63) == 0) { redc[g][tid >> 6] = cnt; redp[g][tid >> 6] = ps; }
  }
  __syncthreads();
  if (tid == 0) {
    float tot = 0.0f, nv = 0.0f;
    for (int g = 0; g < G_; ++g) {
      const float ns = redc[g][0] + redc[g][1] + redc[g][2] + redc[g][3];
      const float pg = redp[g][0] + redp[g][1] + redp[g][2] + redp[g][3];
      if (ns > 0.0f) { tot += pg / fmaxf(ns * ns, 1.0f); nv += 1.0f; }
    }
    out[0] = tot / fmaxf(nv, 1.0f);
  }
}

// ---------------------------------------------------------------------------
extern "C" void kernel_launch(void* const* d_in, const int* in_sizes, int n_in,
                              void* d_out, int out_size, void* d_ws, size_t ws_size,
                              hipStream_t stream) {
  const float* merged = (const float*)d_in[0];
  const float* orig   = (const float*)d_in[1];
  const void*  masks  = (const void*)d_in[2];
  const float* ls     = (const float*)d_in[3];
  const float* lb     = (const float*)d_in[4];
  float* out = (float*)d_out;

  // ws: z1q [G*N*D u8] | z2q [G*N*D u8] | partial [G*1024 f32]
  unsigned char* z1q = (unsigned char*)d_ws;
  unsigned char* z2q = z1q + (size_t)G_ * N_ * D_;
  float* partial = (float*)(z2q + (size_t)G_ * N_ * D_);

  norm_kernel<<<2 * G_ * N_, 256, 0, stream>>>(merged, orig, z1q);
  gemm_loss_kernel<<<dim3(32, 32, G_), 256, 0, stream>>>(z1q, z2q, masks, ls,
                                                         lb, partial);
  finalize_kernel<<<1, 256, 0, stream>>>(masks, partial, out);
}

// Round 4
// 183.426 us; speedup vs baseline: 1.7130x; 1.7130x over previous
//
#include <hip/hip_runtime.h>
#include <hip/hip_bf16.h>
#include <hip/hip_fp8.h>
#include <stdint.h>

#define G_ 4
#define N_ 4096
#define D_ 1024            // K in elements = bytes (fp8)
#define BK_ 128            // K-bytes per LDS tile = one 16x16x128 MFMA K
#define KT_ (D_ / BK_)     // 8 K-iterations
#define MAX_LOGIT_SCALE_F 4.605170185988091f
#define ZSCALE 16.0f       // pre-quantization scale; logits /= ZSCALE^2

typedef float f32x4 __attribute__((ext_vector_type(4)));
typedef int i32x8 __attribute__((ext_vector_type(8)));
typedef __bf16 bf16;

#define AS1 __attribute__((address_space(1)))
#define AS3 __attribute__((address_space(3)))

// ---------------------------------------------------------------------------
// Mask dtype detection (reference dtype bool; harness may store bytes or i32).
// ---------------------------------------------------------------------------
__device__ inline bool mask_is_bytes(const void* masks) {
  const unsigned char* b = (const unsigned char*)masks;
  return (b[1] | b[2] | b[3]) != 0;
}
__device__ inline float mask_val(const void* masks, int idx, bool as_bytes) {
  if (as_bytes) return ((const unsigned char*)masks)[idx] ? 1.0f : 0.0f;
  return ((const int*)masks)[idx] ? 1.0f : 0.0f;
}

// ---------------------------------------------------------------------------
// fp8 e4m3 pack of 4 floats -> u32 (HW cvt if available).
// ---------------------------------------------------------------------------
__device__ inline unsigned int pack4_e4m3(float a, float b, float c, float d) {
#if defined(__has_builtin) && __has_builtin(__builtin_amdgcn_cvt_pk_fp8_f32)
  unsigned int pk = (unsigned int)__builtin_amdgcn_cvt_pk_fp8_f32(a, b, 0, false);
  pk = (unsigned int)__builtin_amdgcn_cvt_pk_fp8_f32(c, d, (int)pk, true);
  return pk;
#else
  __hip_fp8_e4m3 qa(a), qb(b), qc(c), qd(d);
  return (unsigned int)qa.__x | ((unsigned int)qb.__x << 8) |
         ((unsigned int)qc.__x << 16) | ((unsigned int)qd.__x << 24);
#endif
}

// ---------------------------------------------------------------------------
// Kernel 1: L2-normalize rows, scale by 16, quantize to fp8 e4m3, store
// PRE-SWIZZLED (byte e -> e ^ ((row&7)<<4) within each 128-B K-chunk) so the
// linear global_load_lds staging yields a bank-spread LDS layout (rule #21).
// ---------------------------------------------------------------------------
__global__ __launch_bounds__(256) void norm_kernel(
    const float* __restrict__ merged, const float* __restrict__ orig,
    unsigned char* __restrict__ zq) {
  const int row = blockIdx.x;                 // 0 .. 2*G*N-1
  const int GN = G_ * N_;
  const float* src = (row < GN) ? (merged + (size_t)row * D_)
                                : (orig + (size_t)(row - GN) * D_);
  const int tid = threadIdx.x;                // 256 threads, 4 elems each
  float4 v = reinterpret_cast<const float4*>(src)[tid];
  float ss = v.x * v.x + v.y * v.y + v.z * v.z + v.w * v.w;
#pragma unroll
  for (int off = 32; off; off >>= 1) ss += __shfl_down(ss, off, 64);
  __shared__ float wsum[4];
  if ((tid & 63) == 0) wsum[tid >> 6] = ss;
  __syncthreads();
  const float tot = wsum[0] + wsum[1] + wsum[2] + wsum[3];
  const float inv = ZSCALE / fmaxf(sqrtf(tot), 1e-12f);
  const unsigned int pk =
      pack4_e4m3(v.x * inv, v.y * inv, v.z * inv, v.w * inv);
  const int e0 = tid * 4;
  const int off = e0 ^ ((row & 7) << 4);
  *reinterpret_cast<unsigned int*>(zq + (size_t)row * D_ + off) = pk;
}

// ---------------------------------------------------------------------------
// Kernel 2: 128x128-tile MX-fp8 GEMM (z1 . z2^T per group) + fused SigLIP
// loss. m97 2-phase structure (R1-proven): 4 waves (2x2 of 64x64),
// single-buffered LDS, 2 barriers/K-iter, global_load_lds width 16.
// MFMA: mfma_scale_f32_16x16x128_f8f6f4 fp8/fp8, unit scales (E8M0 127).
// R4 regalloc fixes: no K-loop unroll; stream B fragments (hold af[4] only);
// __launch_bounds__(256,3) caps VGPR ~170 (no scratch).
// ---------------------------------------------------------------------------
__global__ __launch_bounds__(256, 3) void gemm_loss_kernel(
    const unsigned char* __restrict__ z1q, const unsigned char* __restrict__ z2q,
    const void* __restrict__ masks,
    const float* __restrict__ p_ls, const float* __restrict__ p_lb,
    float* __restrict__ partial) {
  const int g  = blockIdx.z;
  const int tm = blockIdx.y * 128;
  const int tn = blockIdx.x * 128;
  const unsigned char* A = z1q + ((size_t)g * N_ + tm) * D_;
  const unsigned char* B = z2q + ((size_t)g * N_ + tn) * D_;

  __shared__ __align__(16) unsigned char As[128 * BK_];  // 16 KiB
  __shared__ __align__(16) unsigned char Bs[128 * BK_];  // 16 KiB

  const int tid  = threadIdx.x;
  const int wave = tid >> 6;
  const int lane = tid & 63;
  const int wr = (wave >> 1) * 64;
  const int wc = (wave & 1) * 64;

  f32x4 acc[4][4] = {};

  const int rlo = lane & 15;          // fragment row within 16
  const int kb0 = (lane >> 4) * 32;   // this lane's 32-byte K-chunk base

  auto read_frag = [&](const unsigned char* S, int row) -> i32x8 {
    const int sw = (row & 7) << 4;
    const int4 lo = *reinterpret_cast<const int4*>(S + row * BK_ + (kb0 ^ sw));
    const int4 hi =
        *reinterpret_cast<const int4*>(S + row * BK_ + ((kb0 + 16) ^ sw));
    i32x8 f;
    f[0] = lo.x; f[1] = lo.y; f[2] = lo.z; f[3] = lo.w;
    f[4] = hi.x; f[5] = hi.y; f[6] = hi.z; f[7] = hi.w;
    return f;
  };

#pragma unroll 1
  for (int kt = 0; kt < KT_; ++kt) {
    const int k0 = kt * BK_;
    // stage A,B tiles: 1024 granules of 16 B each, 4 rounds x 256 threads.
    // LDS dest wave-uniform (HW adds lane*16); global source pre-swizzled.
#pragma unroll
    for (int r = 0; r < 4; ++r) {
      const int gr = r * 256 + tid;   // granule index; row = gr/8
      const unsigned char* sa = A + (size_t)(gr >> 3) * D_ + k0 + (gr & 7) * 16;
      __builtin_amdgcn_global_load_lds(
          (const AS1 void*)sa, (AS3 void*)(As + r * 4096 + wave * 1024), 16, 0, 0);
      const unsigned char* sb = B + (size_t)(gr >> 3) * D_ + k0 + (gr & 7) * 16;
      __builtin_amdgcn_global_load_lds(
          (const AS1 void*)sb, (AS3 void*)(Bs + r * 4096 + wave * 1024), 16, 0, 0);
    }
    __syncthreads();  // compiler drains vmcnt before s_barrier

    i32x8 af[4];
#pragma unroll
    for (int i = 0; i < 4; ++i) af[i] = read_frag(As, wr + i * 16 + rlo);

#pragma unroll
    for (int j = 0; j < 4; ++j) {
      const i32x8 bfj = read_frag(Bs, wc + j * 16 + rlo);
#pragma unroll
      for (int i = 0; i < 4; ++i)
        acc[i][j] = __builtin_amdgcn_mfma_scale_f32_16x16x128_f8f6f4(
            af[i], bfj, acc[i][j],
            0, 0,        // cbsz = fp8(e4m3) A, blgp = fp8(e4m3) B
            0, 127,      // opsel_a, scale_a = E8M0 1.0
            0, 127);     // opsel_b, scale_b = E8M0 1.0
    }
    __syncthreads();
  }

  // ---- fused loss epilogue (C/D layout shape-determined: m89/m127) ----
  const float scale = expf(fminf(p_ls[0], MAX_LOGIT_SCALE_F));
  const float s256  = scale * (1.0f / (ZSCALE * ZSCALE));
  const float lbias = p_lb[0];
  const bool as_bytes = mask_is_bytes(masks);
  const int mbase = g * N_;

  const int row0 = tm + wr + ((lane >> 4) << 2);  // + i*16 + j
  const int col0 = tn + wc + (lane & 15);         // + fc*16

  float lsum = 0.0f;
#pragma unroll
  for (int fc = 0; fc < 4; ++fc) {
    const int c = col0 + fc * 16;
    const float mC = mask_val(masks, mbase + c, as_bytes);
#pragma unroll
    for (int i = 0; i < 4; ++i) {
#pragma unroll
      for (int j = 0; j < 4; ++j) {
        const int r = row0 + i * 16 + j;
        const float mR = mask_val(masks, mbase + r, as_bytes);
        const float v = acc[i][fc][j] * s256 + lbias;   // logit
        const float u = (r == c) ? -v : v;              // -label*logit
        const float loss = fmaxf(u, 0.0f) + __logf(1.0f + __expf(-fabsf(u)));
        lsum += mR * mC * loss;
      }
    }
  }

#pragma unroll
  for (int off = 32; off; off >>= 1) lsum += __shfl_down(lsum, off, 64);
  __shared__ float red[4];
  if (lane == 0) red[wave] = lsum;
  __syncthreads();
  if (tid == 0)
    partial[(size_t)g * 1024 + blockIdx.y * 32 + blockIdx.x] =
        red[0] + red[1] + red[2] + red[3];
}

// ---------------------------------------------------------------------------
// Kernel 3: n_sel per group + masked mean over valid groups -> scalar.
// ---------------------------------------------------------------------------
__global__ __launch_bounds__(256) void finalize_kernel(
    const void* __restrict__ masks, const float* __restrict__ partial,
    float* __restrict__ out) {
  const int tid = threadIdx.x;
  const bool as_bytes = mask_is_bytes(masks);
  __shared__ float redc[G_][4];
  __shared__ float redp[G_][4];
  for (int g = 0; g < G_; ++g) {
    float cnt = 0.0f, ps = 0.0f;
    for (int i = tid; i < N_; i += 256) cnt += mask_val(masks, g * N_ + i, as_bytes);
    for (int i = tid; i < 1024; i += 256) ps += partial[g * 1024 + i];
#pragma unroll
    for (int off = 32; off; off >>= 1) {
      cnt += __shfl_down(cnt, off, 64);
      ps  += __shfl_down(ps,  off, 64);
    }
    if ((tid & 63) == 0) { redc[g][tid >> 6] = cnt; redp[g][tid >> 6] = ps; }
  }
  __syncthreads();
  if (tid == 0) {
    float tot = 0.0f, nv = 0.0f;
    for (int g = 0; g < G_; ++g) {
      const float ns = redc[g][0] + redc[g][1] + redc[g][2] + redc[g][3];
      const float pg = redp[g][0] + redp[g][1] + redp[g][2] + redp[g][3];
      if (ns > 0.0f) { tot += pg / fmaxf(ns * ns, 1.0f); nv += 1.0f; }
    }
    out[0] = tot / fmaxf(nv, 1.0f);
  }
}

// ---------------------------------------------------------------------------
extern "C" void kernel_launch(void* const* d_in, const int* in_sizes, int n_in,
                              void* d_out, int out_size, void* d_ws, size_t ws_size,
                              hipStream_t stream) {
  const float* merged = (const float*)d_in[0];
  const float* orig   = (const float*)d_in[1];
  const void*  masks  = (const void*)d_in[2];
  const float* ls     = (const float*)d_in[3];
  const float* lb     = (const float*)d_in[4];
  float* out = (float*)d_out;

  // ws: z1q [G*N*D u8] | z2q [G*N*D u8] | partial [G*1024 f32]
  unsigned char* z1q = (unsigned char*)d_ws;
  unsigned char* z2q = z1q + (size_t)G_ * N_ * D_;
  float* partial = (float*)(z2q + (size_t)G_ * N_ * D_);

  norm_kernel<<<2 * G_ * N_, 256, 0, stream>>>(merged, orig, z1q);
  gemm_loss_kernel<<<dim3(32, 32, G_), 256, 0, stream>>>(z1q, z2q, masks, ls,
                                                         lb, partial);
  finalize_kernel<<<1, 256, 0, stream>>>(masks, partial, out);
}

// Round 5
// 171.303 us; speedup vs baseline: 1.8342x; 1.0708x over previous
//
#include <hip/hip_runtime.h>
#include <hip/hip_bf16.h>
#include <hip/hip_fp8.h>
#include <stdint.h>

#define G_ 4
#define N_ 4096
#define D_ 1024            // K in elements = bytes (fp8)
#define BK_ 128            // K-bytes per tile = one 16x16x128 MFMA K-step
#define KT_ (D_ / BK_)     // 8 K-tiles
#define MAX_LOGIT_SCALE_F 4.605170185988091f
#define ZSCALE 16.0f       // pre-quantization scale; logits /= ZSCALE^2

typedef float f32x4 __attribute__((ext_vector_type(4)));
typedef int i32x8 __attribute__((ext_vector_type(8)));

#define AS1 __attribute__((address_space(1)))
#define AS3 __attribute__((address_space(3)))

// ---------------------------------------------------------------------------
// Mask dtype detection (reference dtype bool; harness may store bytes or i32).
// ---------------------------------------------------------------------------
__device__ inline bool mask_is_bytes(const void* masks) {
  const unsigned char* b = (const unsigned char*)masks;
  return (b[1] | b[2] | b[3]) != 0;
}
__device__ inline float mask_val(const void* masks, int idx, bool as_bytes) {
  if (as_bytes) return ((const unsigned char*)masks)[idx] ? 1.0f : 0.0f;
  return ((const int*)masks)[idx] ? 1.0f : 0.0f;
}

// ---------------------------------------------------------------------------
// fp8 e4m3 pack of 4 floats -> u32.
// ---------------------------------------------------------------------------
__device__ inline unsigned int pack4_e4m3(float a, float b, float c, float d) {
#if defined(__has_builtin) && __has_builtin(__builtin_amdgcn_cvt_pk_fp8_f32)
  unsigned int pk = (unsigned int)__builtin_amdgcn_cvt_pk_fp8_f32(a, b, 0, false);
  pk = (unsigned int)__builtin_amdgcn_cvt_pk_fp8_f32(c, d, (int)pk, true);
  return pk;
#else
  __hip_fp8_e4m3 qa(a), qb(b), qc(c), qd(d);
  return (unsigned int)qa.__x | ((unsigned int)qb.__x << 8) |
         ((unsigned int)qc.__x << 16) | ((unsigned int)qd.__x << 24);
#endif
}

// ---------------------------------------------------------------------------
// Kernel 1: L2-normalize rows, scale by 16, quantize to fp8 e4m3, store
// PRE-SWIZZLED (byte e -> e ^ ((row&7)<<4) within each 128-B K-chunk) so the
// linear global_load_lds staging yields a bank-spread LDS layout (rule #21).
// ---------------------------------------------------------------------------
__global__ __launch_bounds__(256) void norm_kernel(
    const float* __restrict__ merged, const float* __restrict__ orig,
    unsigned char* __restrict__ zq) {
  const int row = blockIdx.x;                 // 0 .. 2*G*N-1
  const int GN = G_ * N_;
  const float* src = (row < GN) ? (merged + (size_t)row * D_)
                                : (orig + (size_t)(row - GN) * D_);
  const int tid = threadIdx.x;                // 256 threads, 4 elems each
  float4 v = reinterpret_cast<const float4*>(src)[tid];
  float ss = v.x * v.x + v.y * v.y + v.z * v.z + v.w * v.w;
#pragma unroll
  for (int off = 32; off; off >>= 1) ss += __shfl_down(ss, off, 64);
  __shared__ float wsum[4];
  if ((tid & 63) == 0) wsum[tid >> 6] = ss;
  __syncthreads();
  const float tot = wsum[0] + wsum[1] + wsum[2] + wsum[3];
  const float inv = ZSCALE / fmaxf(sqrtf(tot), 1e-12f);
  const unsigned int pk =
      pack4_e4m3(v.x * inv, v.y * inv, v.z * inv, v.w * inv);
  const int e0 = tid * 4;
  const int off = e0 ^ ((row & 7) << 4);
  *reinterpret_cast<unsigned int*>(zq + (size_t)row * D_ + off) = pk;
}

// ---------------------------------------------------------------------------
// Kernel 2: 256x256-tile MX-fp8 GEMM + fused SigLIP loss, m201-style 4-phase
// schedule. 8 waves (2M x 4N; per-wave out 128x64 = 8x4 16x16 frags).
// Per K-tile (BK=128 B): 4 phases, each {ds_read subtile | stage -> raw
// barrier -> lgkmcnt(0) -> setprio(1) 8 MFMA setprio(0) -> barrier}.
// Stage of tile t+1 front-loaded into P1(A)/P2(B); single vmcnt(0) at P4
// with >=2 phases of MFMA cover. 2 LDS buffers (128 KiB), 1 block/CU.
// ---------------------------------------------------------------------------
__global__ __launch_bounds__(512, 2) void gemm_loss_kernel(
    const unsigned char* __restrict__ z1q, const unsigned char* __restrict__ z2q,
    const void* __restrict__ masks,
    const float* __restrict__ p_ls, const float* __restrict__ p_lb,
    float* __restrict__ partial) {
  // [buf][A 256x128 | B 256x128] bytes = 2 * 65536 = 128 KiB
  __shared__ __align__(16) unsigned char sh[2 * 65536];

  const int g  = blockIdx.z;
  const int tm = blockIdx.y * 256;
  const int tn = blockIdx.x * 256;
  const unsigned char* Abase = z1q + ((size_t)g * N_ + tm) * D_;
  const unsigned char* Bbase = z2q + ((size_t)g * N_ + tn) * D_;

  const int tid  = threadIdx.x;
  const int wave = tid >> 6;
  const int lane = tid & 63;
  const int wm = wave >> 2;    // 0..1 -> rows wm*128
  const int wn = wave & 3;     // 0..3 -> cols wn*64

  const int rlo = lane & 15;
  const int kb0 = (lane >> 4) * 32;   // lane's 32-byte K-chunk base

  f32x4 acc[8][4] = {};

  // stage one 32-KB operand tile (256 rows x 128 B): 2048 granules of 16 B,
  // 4 rounds x 512 threads. Dest wave-uniform (HW adds lane*16); global
  // source pre-swizzled by norm_kernel.
  auto stage_op = [&](const unsigned char* src, unsigned char* dst, int kt) {
    const int k0 = kt * BK_;
#pragma unroll
    for (int r = 0; r < 4; ++r) {
      const int gr = r * 512 + tid;
      const unsigned char* s = src + (size_t)(gr >> 3) * D_ + k0 + (gr & 7) * 16;
      __builtin_amdgcn_global_load_lds(
          (const AS1 void*)s, (AS3 void*)(dst + r * 8192 + wave * 1024), 16, 0, 0);
    }
  };

  auto read_frag = [&](const unsigned char* S, int row) -> i32x8 {
    const int sw = (row & 7) << 4;
    const int4 lo = *reinterpret_cast<const int4*>(S + row * BK_ + (kb0 ^ sw));
    const int4 hi =
        *reinterpret_cast<const int4*>(S + row * BK_ + ((kb0 + 16) ^ sw));
    i32x8 f;
    f[0] = lo.x; f[1] = lo.y; f[2] = lo.z; f[3] = lo.w;
    f[4] = hi.x; f[5] = hi.y; f[6] = hi.z; f[7] = hi.w;
    return f;
  };

#define MFMA_FP8(a, b, c) \
  __builtin_amdgcn_mfma_scale_f32_16x16x128_f8f6f4((a), (b), (c), 0, 0, 0, 127, 0, 127)

  // prologue: stage tile 0, full drain once, sync.
  stage_op(Abase, sh, 0);
  stage_op(Bbase, sh + 32768, 0);
  asm volatile("s_waitcnt vmcnt(0)" ::: "memory");
  __builtin_amdgcn_sched_barrier(0);
  __builtin_amdgcn_s_barrier();

#pragma unroll 1
  for (int kt = 0; kt < KT_; ++kt) {
    const unsigned char* bufR = sh + (kt & 1) * 65536;
    unsigned char* bufW = sh + ((kt + 1) & 1) * 65536;
    const unsigned char* sA = bufR;
    const unsigned char* sB = bufR + 32768;
    const bool more = (kt + 1 < KT_);

    i32x8 a03[4], a47[4], b01[2], b23[2];

    // ---- P1: read a0-3,b0-1 | stage next-A | MFMA m0-3 x n0-1 ----
#pragma unroll
    for (int i = 0; i < 4; ++i) a03[i] = read_frag(sA, wm * 128 + i * 16 + rlo);
#pragma unroll
    for (int j = 0; j < 2; ++j) b01[j] = read_frag(sB, wn * 64 + j * 16 + rlo);
    if (more) stage_op(Abase, bufW, kt + 1);
    __builtin_amdgcn_s_barrier();
    asm volatile("s_waitcnt lgkmcnt(0)" ::: "memory");
    __builtin_amdgcn_sched_barrier(0);
    __builtin_amdgcn_s_setprio(1);
#pragma unroll
    for (int i = 0; i < 4; ++i)
#pragma unroll
      for (int j = 0; j < 2; ++j)
        acc[i][j] = MFMA_FP8(a03[i], b01[j], acc[i][j]);
    __builtin_amdgcn_s_setprio(0);
    __builtin_amdgcn_s_barrier();

    // ---- P2: read b2-3 | stage next-B | MFMA m0-3 x n2-3 ----
#pragma unroll
    for (int j = 0; j < 2; ++j)
      b23[j] = read_frag(sB, wn * 64 + (j + 2) * 16 + rlo);
    if (more) stage_op(Bbase, bufW + 32768, kt + 1);
    __builtin_amdgcn_s_barrier();
    asm volatile("s_waitcnt lgkmcnt(0)" ::: "memory");
    __builtin_amdgcn_sched_barrier(0);
    __builtin_amdgcn_s_setprio(1);
#pragma unroll
    for (int i = 0; i < 4; ++i)
#pragma unroll
      for (int j = 0; j < 2; ++j)
        acc[i][j + 2] = MFMA_FP8(a03[i], b23[j], acc[i][j + 2]);
    __builtin_amdgcn_s_setprio(0);
    __builtin_amdgcn_s_barrier();

    // ---- P3: read a4-7 | MFMA m4-7 x n2-3 ----
#pragma unroll
    for (int i = 0; i < 4; ++i)
      a47[i] = read_frag(sA, wm * 128 + (i + 4) * 16 + rlo);
    __builtin_amdgcn_s_barrier();
    asm volatile("s_waitcnt lgkmcnt(0)" ::: "memory");
    __builtin_amdgcn_sched_barrier(0);
    __builtin_amdgcn_s_setprio(1);
#pragma unroll
    for (int i = 0; i < 4; ++i)
#pragma unroll
      for (int j = 0; j < 2; ++j)
        acc[i + 4][j + 2] = MFMA_FP8(a47[i], b23[j], acc[i + 4][j + 2]);
    __builtin_amdgcn_s_setprio(0);
    __builtin_amdgcn_s_barrier();

    // ---- P4: drain next-tile stages (>=2 phases of cover) | MFMA m4-7 x n0-1
    asm volatile("s_waitcnt vmcnt(0)" ::: "memory");
    __builtin_amdgcn_sched_barrier(0);
    __builtin_amdgcn_s_barrier();
    __builtin_amdgcn_s_setprio(1);
#pragma unroll
    for (int i = 0; i < 4; ++i)
#pragma unroll
      for (int j = 0; j < 2; ++j)
        acc[i + 4][j] = MFMA_FP8(a47[i], b01[j], acc[i + 4][j]);
    __builtin_amdgcn_s_setprio(0);
    __builtin_amdgcn_s_barrier();
  }
#undef MFMA_FP8

  // ---- fused loss epilogue (C/D layout shape-determined: m89/m127) ----
  const float scale = expf(fminf(p_ls[0], MAX_LOGIT_SCALE_F));
  const float s256  = scale * (1.0f / (ZSCALE * ZSCALE));
  const float lbias = p_lb[0];
  const bool as_bytes = mask_is_bytes(masks);
  const int mbase = g * N_;

  const int row0 = tm + wm * 128 + ((lane >> 4) << 2);  // + fm*16 + j
  const int col0 = tn + wn * 64 + (lane & 15);          // + fc*16

  float mC[4];
#pragma unroll
  for (int fc = 0; fc < 4; ++fc)
    mC[fc] = mask_val(masks, mbase + col0 + fc * 16, as_bytes);

  float lsum = 0.0f;
#pragma unroll
  for (int fm = 0; fm < 8; ++fm) {
#pragma unroll
    for (int j = 0; j < 4; ++j) {
      const int r = row0 + fm * 16 + j;
      const float mR = mask_val(masks, mbase + r, as_bytes);
#pragma unroll
      for (int fc = 0; fc < 4; ++fc) {
        const int c = col0 + fc * 16;
        const float v = acc[fm][fc][j] * s256 + lbias;  // logit
        const float u = (r == c) ? -v : v;              // -label*logit
        const float loss = fmaxf(u, 0.0f) + __logf(1.0f + __expf(-fabsf(u)));
        lsum += mR * mC[fc] * loss;
      }
    }
  }

#pragma unroll
  for (int off = 32; off; off >>= 1) lsum += __shfl_down(lsum, off, 64);
  float* red = (float*)sh;  // LDS reads all complete (last barrier passed)
  if (lane == 0) red[wave] = lsum;
  __syncthreads();
  if (tid == 0) {
    float s = 0.0f;
#pragma unroll
    for (int w = 0; w < 8; ++w) s += red[w];
    partial[((size_t)g * 16 + blockIdx.y) * 16 + blockIdx.x] = s;
  }
}

// ---------------------------------------------------------------------------
// Kernel 3: n_sel per group + masked mean over valid groups -> scalar.
// ---------------------------------------------------------------------------
__global__ __launch_bounds__(256) void finalize_kernel(
    const void* __restrict__ masks, const float* __restrict__ partial,
    float* __restrict__ out) {
  const int tid = threadIdx.x;
  const bool as_bytes = mask_is_bytes(masks);
  __shared__ float redc[G_][4];
  __shared__ float redp[G_][4];
  for (int g = 0; g < G_; ++g) {
    float cnt = 0.0f, ps = 0.0f;
    for (int i = tid; i < N_; i += 256) cnt += mask_val(masks, g * N_ + i, as_bytes);
    for (int i = tid; i < 256; i += 256) ps += partial[g * 256 + i];
#pragma unroll
    for (int off = 32; off; off >>= 1) {
      cnt += __shfl_down(cnt, off, 64);
      ps  += __shfl_down(ps,  off, 64);
    }
    if ((tid & 63) == 0) { redc[g][tid >> 6] = cnt; redp[g][tid >> 6] = ps; }
  }
  __syncthreads();
  if (tid == 0) {
    float tot = 0.0f, nv = 0.0f;
    for (int g = 0; g < G_; ++g) {
      const float ns = redc[g][0] + redc[g][1] + redc[g][2] + redc[g][3];
      const float pg = redp[g][0] + redp[g][1] + redp[g][2] + redp[g][3];
      if (ns > 0.0f) { tot += pg / fmaxf(ns * ns, 1.0f); nv += 1.0f; }
    }
    out[0] = tot / fmaxf(nv, 1.0f);
  }
}

// ---------------------------------------------------------------------------
extern "C" void kernel_launch(void* const* d_in, const int* in_sizes, int n_in,
                              void* d_out, int out_size, void* d_ws, size_t ws_size,
                              hipStream_t stream) {
  const float* merged = (const float*)d_in[0];
  const float* orig   = (const float*)d_in[1];
  const void*  masks  = (const void*)d_in[2];
  const float* ls     = (const float*)d_in[3];
  const float* lb     = (const float*)d_in[4];
  float* out = (float*)d_out;

  // ws: z1q [G*N*D u8] | z2q [G*N*D u8] | partial [G*256 f32]
  unsigned char* z1q = (unsigned char*)d_ws;
  unsigned char* z2q = z1q + (size_t)G_ * N_ * D_;
  float* partial = (float*)(z2q + (size_t)G_ * N_ * D_);

  norm_kernel<<<2 * G_ * N_, 256, 0, stream>>>(merged, orig, z1q);
  gemm_loss_kernel<<<dim3(16, 16, G_), 512, 0, stream>>>(z1q, z2q, masks, ls,
                                                         lb, partial);
  finalize_kernel<<<1, 256, 0, stream>>>(masks, partial, out);
}